// Round 1
// baseline (324.274 us; speedup 1.0000x reference)
//
#include <hip/hip_runtime.h>
#include <math.h>

#define IMG 416
#define N_ANG 320
#define N_DET 416
#define N_SAMP 416

// ---------------------------------------------------------------------------
// Kernel A: diff image (input - target) into workspace; also zero the output
// accumulator (harness poisons d_out with 0xAA before every launch).
// ---------------------------------------------------------------------------
__global__ __launch_bounds__(256) void diff_kernel(const float* __restrict__ a,
                                                   const float* __restrict__ b,
                                                   float* __restrict__ d,
                                                   float* __restrict__ out) {
    int i = blockIdx.x * 256 + threadIdx.x;
    if (i < IMG * IMG) d[i] = a[i] - b[i];
    if (i == 0) out[0] = 0.0f;
}

// Fallback when ws is too small: just zero the output.
__global__ void zero_out_kernel(float* __restrict__ out) {
    if (threadIdx.x == 0) out[0] = 0.0f;
}

// ---------------------------------------------------------------------------
// Kernel B: one thread per ray (angle, det). March N_SAMP samples, bilinear
// sample the (diff) image with zero padding, accumulate the line integral,
// square it, block-reduce, one atomicAdd per block with all scaling folded in.
// FUSED=true samples (imgA - imgB) on the fly (no workspace needed).
// ---------------------------------------------------------------------------
template <bool FUSED>
__global__ __launch_bounds__(256) void proj_kernel(const float* __restrict__ imgA,
                                                   const float* __restrict__ imgB,
                                                   float* __restrict__ out,
                                                   float theta_step, float gmax,
                                                   float gstep, float t0,
                                                   float dtstep, float coef) {
    const int idx = blockIdx.x * 256 + threadIdx.x;   // 0 .. 320*416-1 exactly
    const int a  = idx / N_DET;
    const int dd = idx - a * N_DET;

    const float theta = (float)a * theta_step;
    const float gamma = fmaf((float)dd, gstep, -gmax);

    float s1, c1, s2, c2;
    sincosf(theta, &s1, &c1);
    sincosf(theta + gamma, &s2, &c2);

    const float sx = 1075.0f * c1 + 207.5f;   // fold +ctr into source position
    const float sy = 1075.0f * s1 + 207.5f;

    float acc = 0.0f;
    #pragma unroll 4
    for (int s = 0; s < N_SAMP; ++s) {
        const float t   = fmaf((float)s, dtstep, t0);
        const float col = fmaf(-t, c2, sx);
        const float row = fmaf(-t, s2, sy);

        const float c0 = floorf(col);
        const float r0 = floorf(row);
        const float wc = col - c0;
        const float wr = row - r0;
        const int ci = (int)c0;
        const int ri = (int)r0;

        auto G = [&](int r, int c) -> float {
            if ((unsigned)r < (unsigned)IMG && (unsigned)c < (unsigned)IMG) {
                float v = imgA[r * IMG + c];
                if (FUSED) v -= imgB[r * IMG + c];
                return v;
            }
            return 0.0f;
        };

        const float v00 = G(ri, ci);
        const float v01 = G(ri, ci + 1);
        const float v10 = G(ri + 1, ci);
        const float v11 = G(ri + 1, ci + 1);

        const float top = fmaf(wc, v01 - v00, v00);
        const float bot = fmaf(wc, v11 - v10, v10);
        acc += fmaf(wr, bot - top, top);
    }

    // (line integral)^2; dt, SCALE, and 1/(N_ANG*N_DET) are folded into coef.
    float sq = acc * acc;

    // wave64 shuffle reduction
    #pragma unroll
    for (int o = 32; o > 0; o >>= 1) sq += __shfl_down(sq, o, 64);

    __shared__ float wsum[4];
    const int lane = threadIdx.x & 63;
    const int wv   = threadIdx.x >> 6;
    if (lane == 0) wsum[wv] = sq;
    __syncthreads();
    if (threadIdx.x == 0) {
        const float bsum = (wsum[0] + wsum[1]) + (wsum[2] + wsum[3]);
        atomicAdd(out, bsum * coef);
    }
}

extern "C" void kernel_launch(void* const* d_in, const int* in_sizes, int n_in,
                              void* d_out, int out_size, void* d_ws, size_t ws_size,
                              hipStream_t stream) {
    const float* in = (const float*)d_in[0];
    const float* tg = (const float*)d_in[1];
    float* out = (float*)d_out;

    // Host-side constants in double, cast to float (mirrors np.float32(...)).
    const double half_diag = (IMG / 2.0) * sqrt(2.0);
    const double ray_len   = IMG * sqrt(2.0);
    const float  gmax      = (float)asin(half_diag / 1075.0);
    const float  gstep     = (float)(2.0 * (double)gmax / (N_DET - 1));
    const float  t0        = (float)(1075.0 - ray_len / 2.0);
    const float  dtstep    = (float)(ray_len / (N_SAMP - 1));
    const float  theta_step = (float)(2.0 * M_PI / N_ANG);
    const double dt        = ray_len / (N_SAMP - 1);
    const double SCALE     = 512.0 / 416.0 * 0.03;
    const float  coef      = (float)(dt * dt * SCALE / ((double)N_ANG * N_DET));

    const int n_rays   = N_ANG * N_DET;            // 133120 = 520 * 256
    const int n_pix    = IMG * IMG;                // 173056 = 676 * 256
    const bool use_ws  = ws_size >= (size_t)n_pix * sizeof(float);

    if (use_ws) {
        float* diff = (float*)d_ws;
        diff_kernel<<<(n_pix + 255) / 256, 256, 0, stream>>>(in, tg, diff, out);
        proj_kernel<false><<<n_rays / 256, 256, 0, stream>>>(
            diff, nullptr, out, theta_step, gmax, gstep, t0, dtstep, coef);
    } else {
        zero_out_kernel<<<1, 64, 0, stream>>>(out);
        proj_kernel<true><<<n_rays / 256, 256, 0, stream>>>(
            in, tg, out, theta_step, gmax, gstep, t0, dtstep, coef);
    }
}

// Round 2
// 122.528 us; speedup vs baseline: 2.6465x; 2.6465x over previous
//
#include <hip/hip_runtime.h>
#include <math.h>

#define IMG 416
#define N_ANG 320
#define N_DET 416
#define N_SAMP 416

// Packed quad table: rows pr=0..417 map to r0=pr-1 in [-1,416];
// cols pc=0..431 (STRIDE), valid pc=0..417 map to c0=pc-1; rest zero pad.
// Entry = {bf16 v(r0,c0) | bf16 v(r0,c0+1)<<16 , bf16 v(r0+1,c0) | bf16 v(r0+1,c0+1)<<16}
// where v = zero-padded diff image. STRIDE=432 keeps rows 64B-aligned.
#define PSTRIDE 432
#define PROWS   418
#define PBYTES  ((size_t)PROWS * PSTRIDE * 8)

static __device__ __forceinline__ unsigned int f2bf(float f) {
    unsigned int x = __float_as_uint(f);
    return (x + 0x7fffu + ((x >> 16) & 1u)) >> 16;   // RNE to bf16, NaN-free input
}

// ---------------------------------------------------------------------------
// Kernel A: build the packed quad table from (input - target); zero d_out.
// ---------------------------------------------------------------------------
__global__ __launch_bounds__(256) void pack_kernel(const float* __restrict__ a,
                                                   const float* __restrict__ b,
                                                   uint2* __restrict__ P,
                                                   float* __restrict__ out) {
    int i = blockIdx.x * 256 + threadIdx.x;
    if (i == 0) out[0] = 0.0f;
    if (i >= PROWS * PSTRIDE) return;
    int pr = i / PSTRIDE;
    int pc = i - pr * PSTRIDE;
    int r = pr - 1, c = pc - 1;
    float v00 = 0.f, v01 = 0.f, v10 = 0.f, v11 = 0.f;
    bool c0in = (unsigned)c < (unsigned)IMG;
    bool c1in = (unsigned)(c + 1) < (unsigned)IMG;
    if ((unsigned)r < (unsigned)IMG) {
        int base = r * IMG;
        if (c0in) v00 = a[base + c] - b[base + c];
        if (c1in) v01 = a[base + c + 1] - b[base + c + 1];
    }
    if ((unsigned)(r + 1) < (unsigned)IMG) {
        int base = (r + 1) * IMG;
        if (c0in) v10 = a[base + c] - b[base + c];
        if (c1in) v11 = a[base + c + 1] - b[base + c + 1];
    }
    uint2 u;
    u.x = f2bf(v00) | (f2bf(v01) << 16);
    u.y = f2bf(v10) | (f2bf(v11) << 16);
    P[i] = u;
}

__global__ void zero_out_kernel(float* __restrict__ out) {
    if (threadIdx.x == 0) out[0] = 0.0f;
}

// ---------------------------------------------------------------------------
// Kernel B: wave = 8 detectors x 8 sample-phases. One dwordx2 gather per
// bilinear sample. Butterfly-reduce samples -> square -> butterfly dets ->
// LDS -> one atomicAdd per block.
// ---------------------------------------------------------------------------
__global__ __launch_bounds__(256) void proj_packed(const uint2* __restrict__ P,
                                                   float* __restrict__ out,
                                                   float theta_step, float gmax,
                                                   float gstep, float t0,
                                                   float dtstep, float coef) {
    const int lane = threadIdx.x & 63;
    const int wave = (blockIdx.x * 256 + threadIdx.x) >> 6;
    const int det_base = wave << 3;              // 8 dets per wave; 416%8==0 -> no straddle
    const int a  = det_base / N_DET;
    const int d  = det_base - a * N_DET + (lane >> 3);
    const int s0 = lane & 7;

    const float theta = (float)a * theta_step;
    const float gamma = fmaf((float)d, gstep, -gmax);
    float s1, c1, s2, c2;
    sincosf(theta, &s1, &c1);
    sincosf(theta + gamma, &s2, &c2);
    const float sx = fmaf(1075.0f, c1, 207.5f);
    const float sy = fmaf(1075.0f, s1, 207.5f);

    const uint2* __restrict__ Pb = P + (PSTRIDE + 1);   // fold the +1 row/col pad offset
    const float tstart = fmaf((float)s0, dtstep, t0);
    const float dt8 = 8.0f * dtstep;

    float acc = 0.0f;
    #pragma unroll 4
    for (int k = 0; k < N_SAMP / 8; ++k) {
        const float t   = fmaf((float)k, dt8, tstart);
        const float col = fmaf(-t, c2, sx);
        const float row = fmaf(-t, s2, sy);
        // branch-free clamp into the zero-pad ring: indices land in [-1,416]
        const float colc = fminf(fmaxf(col, -1.0f), 416.5f);
        const float rowc = fminf(fmaxf(row, -1.0f), 416.5f);
        const int ci = (int)floorf(colc);
        const int ri = (int)floorf(rowc);
        const float wc = colc - (float)ci;
        const float wr = rowc - (float)ri;

        const uint2 u = Pb[ri * PSTRIDE + ci];
        const float v00 = __uint_as_float(u.x << 16);
        const float v01 = __uint_as_float(u.x & 0xffff0000u);
        const float v10 = __uint_as_float(u.y << 16);
        const float v11 = __uint_as_float(u.y & 0xffff0000u);

        const float top = fmaf(wc, v01 - v00, v00);
        const float bot = fmaf(wc, v11 - v10, v10);
        acc = fmaf(wr, bot - top, acc + top);
    }

    // sum over the 8 sample-phases (lane bits 0-2)
    #pragma unroll
    for (int m = 1; m < 8; m <<= 1) acc += __shfl_xor(acc, m, 64);
    float sq = acc * acc;           // identical across each det's 8 lanes
    // sum over the 8 det groups (lane bits 3-5): each group counted once
    #pragma unroll
    for (int m = 8; m < 64; m <<= 1) sq += __shfl_xor(sq, m, 64);

    __shared__ float wsum[4];
    if (lane == 0) wsum[threadIdx.x >> 6] = sq;
    __syncthreads();
    if (threadIdx.x == 0)
        atomicAdd(out, (wsum[0] + wsum[1] + wsum[2] + wsum[3]) * coef);
}

// ---------------------------------------------------------------------------
// Fallback (ws too small): fused one-thread-per-ray fp32 gather version.
// ---------------------------------------------------------------------------
__global__ __launch_bounds__(256) void proj_fused(const float* __restrict__ imgA,
                                                  const float* __restrict__ imgB,
                                                  float* __restrict__ out,
                                                  float theta_step, float gmax,
                                                  float gstep, float t0,
                                                  float dtstep, float coef) {
    const int idx = blockIdx.x * 256 + threadIdx.x;
    const int a  = idx / N_DET;
    const int dd = idx - a * N_DET;
    const float theta = (float)a * theta_step;
    const float gamma = fmaf((float)dd, gstep, -gmax);
    float s1, c1, s2, c2;
    sincosf(theta, &s1, &c1);
    sincosf(theta + gamma, &s2, &c2);
    const float sx = 1075.0f * c1 + 207.5f;
    const float sy = 1075.0f * s1 + 207.5f;
    float acc = 0.0f;
    #pragma unroll 4
    for (int s = 0; s < N_SAMP; ++s) {
        const float t   = fmaf((float)s, dtstep, t0);
        const float col = fmaf(-t, c2, sx);
        const float row = fmaf(-t, s2, sy);
        const float c0 = floorf(col);
        const float r0 = floorf(row);
        const float wc = col - c0;
        const float wr = row - r0;
        const int ci = (int)c0;
        const int ri = (int)r0;
        auto G = [&](int r, int c) -> float {
            if ((unsigned)r < (unsigned)IMG && (unsigned)c < (unsigned)IMG)
                return imgA[r * IMG + c] - imgB[r * IMG + c];
            return 0.0f;
        };
        const float v00 = G(ri, ci);
        const float v01 = G(ri, ci + 1);
        const float v10 = G(ri + 1, ci);
        const float v11 = G(ri + 1, ci + 1);
        const float top = fmaf(wc, v01 - v00, v00);
        const float bot = fmaf(wc, v11 - v10, v10);
        acc += fmaf(wr, bot - top, top);
    }
    float sq = acc * acc;
    #pragma unroll
    for (int o = 32; o > 0; o >>= 1) sq += __shfl_down(sq, o, 64);
    __shared__ float wsum[4];
    const int lane = threadIdx.x & 63;
    if (lane == 0) wsum[threadIdx.x >> 6] = sq;
    __syncthreads();
    if (threadIdx.x == 0)
        atomicAdd(out, (wsum[0] + wsum[1] + wsum[2] + wsum[3]) * coef);
}

extern "C" void kernel_launch(void* const* d_in, const int* in_sizes, int n_in,
                              void* d_out, int out_size, void* d_ws, size_t ws_size,
                              hipStream_t stream) {
    const float* in = (const float*)d_in[0];
    const float* tg = (const float*)d_in[1];
    float* out = (float*)d_out;

    const double half_diag = (IMG / 2.0) * sqrt(2.0);
    const double ray_len   = IMG * sqrt(2.0);
    const float  gmax      = (float)asin(half_diag / 1075.0);
    const float  gstep     = (float)(2.0 * (double)gmax / (N_DET - 1));
    const float  t0        = (float)(1075.0 - ray_len / 2.0);
    const float  dtstep    = (float)(ray_len / (N_SAMP - 1));
    const float  theta_step = (float)(2.0 * M_PI / N_ANG);
    const double dt        = ray_len / (N_SAMP - 1);
    const double SCALE     = 512.0 / 416.0 * 0.03;
    const float  coef      = (float)(dt * dt * SCALE / ((double)N_ANG * N_DET));

    const int n_rays = N_ANG * N_DET;            // 133120
    if (ws_size >= PBYTES) {
        uint2* P = (uint2*)d_ws;
        const int n_ent = PROWS * PSTRIDE;
        pack_kernel<<<(n_ent + 255) / 256, 256, 0, stream>>>(in, tg, P, out);
        // 8 dets/wave -> 16640 waves -> 4160 blocks of 4 waves
        proj_packed<<<(n_rays / 8) / 4, 256, 0, stream>>>(
            P, out, theta_step, gmax, gstep, t0, dtstep, coef);
    } else {
        zero_out_kernel<<<1, 64, 0, stream>>>(out);
        proj_fused<<<n_rays / 256, 256, 0, stream>>>(
            in, tg, out, theta_step, gmax, gstep, t0, dtstep, coef);
    }
}

// Round 3
// 115.069 us; speedup vs baseline: 2.8181x; 1.0648x over previous
//
#include <hip/hip_runtime.h>
#include <math.h>

#define IMG 416
#define N_ANG 320
#define N_DET 416
#define N_SAMP 416
#define NK (N_SAMP / 8)          // 52 sample-blocks per phase lane

// Packed quad table: rows pr=0..417 map to r0=pr-1 in [-1,416];
// cols pc=0..431 (STRIDE), valid pc=0..417 map to c0=pc-1; rest zero pad.
// Entry = {bf16 v(r0,c0) | bf16 v(r0,c0+1)<<16 , bf16 v(r0+1,c0) | bf16 v(r0+1,c0+1)<<16}
// where v = zero-padded diff image. STRIDE=432 keeps rows 64B-aligned.
#define PSTRIDE 432
#define PROWS   418
#define PBYTES  ((size_t)PROWS * PSTRIDE * 8)

static __device__ __forceinline__ unsigned int f2bf(float f) {
    unsigned int x = __float_as_uint(f);
    return (x + 0x7fffu + ((x >> 16) & 1u)) >> 16;   // RNE to bf16, NaN-free input
}

// ---------------------------------------------------------------------------
// Kernel A: build the packed quad table from (input - target); zero d_out.
// ---------------------------------------------------------------------------
__global__ __launch_bounds__(256) void pack_kernel(const float* __restrict__ a,
                                                   const float* __restrict__ b,
                                                   uint2* __restrict__ P,
                                                   float* __restrict__ out) {
    int i = blockIdx.x * 256 + threadIdx.x;
    if (i == 0) out[0] = 0.0f;
    if (i >= PROWS * PSTRIDE) return;
    int pr = i / PSTRIDE;
    int pc = i - pr * PSTRIDE;
    int r = pr - 1, c = pc - 1;
    float v00 = 0.f, v01 = 0.f, v10 = 0.f, v11 = 0.f;
    bool c0in = (unsigned)c < (unsigned)IMG;
    bool c1in = (unsigned)(c + 1) < (unsigned)IMG;
    if ((unsigned)r < (unsigned)IMG) {
        int base = r * IMG;
        if (c0in) v00 = a[base + c] - b[base + c];
        if (c1in) v01 = a[base + c + 1] - b[base + c + 1];
    }
    if ((unsigned)(r + 1) < (unsigned)IMG) {
        int base = (r + 1) * IMG;
        if (c0in) v10 = a[base + c] - b[base + c];
        if (c1in) v11 = a[base + c + 1] - b[base + c + 1];
    }
    uint2 u;
    u.x = f2bf(v00) | (f2bf(v01) << 16);
    u.y = f2bf(v10) | (f2bf(v11) << 16);
    P[i] = u;
}

__global__ void zero_out_kernel(float* __restrict__ out) {
    if (threadIdx.x == 0) out[0] = 0.0f;
}

// ---------------------------------------------------------------------------
// Kernel B: wave = 8 detectors x 8 sample-phases. Per-ray slab clip to the
// image box -> wave-uniform scalar k-loop over only in-image samples.
// One dwordx2 gather per bilinear sample; clamp+pad-ring keeps boundary
// iterations exact. Butterfly reduce -> square -> LDS -> 1 atomic/block.
// ---------------------------------------------------------------------------
__global__ __launch_bounds__(256) void proj_packed(const uint2* __restrict__ P,
                                                   float* __restrict__ out,
                                                   float theta_step, float gmax,
                                                   float gstep, float t0,
                                                   float dtstep, float coef) {
    const int lane = threadIdx.x & 63;
    const int wave = (blockIdx.x * 256 + threadIdx.x) >> 6;
    const int det_base = wave << 3;              // 8 dets/wave; 416%8==0 -> no straddle
    const int a  = det_base / N_DET;
    const int d  = det_base - a * N_DET + (lane >> 3);
    const int s0 = lane & 7;

    const float theta = (float)a * theta_step;
    const float gamma = fmaf((float)d, gstep, -gmax);
    float s1, c1, s2, c2;
    sincosf(theta, &s1, &c1);
    sincosf(theta + gamma, &s2, &c2);
    const float sx = fmaf(1075.0f, c1, 207.5f);
    const float sy = fmaf(1075.0f, s1, 207.5f);

    const float dt8 = 8.0f * dtstep;
    const float tstart = fmaf((float)s0, dtstep, t0);

    // --- slab clip: t-range where col,row could touch nonzero pixels -------
    const float c2g = (fabsf(c2) < 1e-12f) ? 1e-12f : c2;
    const float s2g = (fabsf(s2) < 1e-12f) ? 1e-12f : s2;
    const float ix = 1.0f / c2g, iy = 1.0f / s2g;
    const float tax = (sx - 416.5f) * ix, tbx = (sx + 1.5f) * ix;
    const float tay = (sy - 416.5f) * iy, tby = (sy + 1.5f) * iy;
    const float t_lo = fmaxf(fminf(tax, tbx), fminf(tay, tby));
    const float t_hi = fminf(fmaxf(tax, tbx), fmaxf(tay, tby));

    const float inv_dt8 = 1.0f / dt8;
    int klo = (int)floorf((t_lo - tstart) * inv_dt8);   // conservative widen
    int khi = (int)ceilf((t_hi - tstart) * inv_dt8);
    klo = max(0, min(klo, NK));
    khi = min(NK - 1, khi);

    // wave-uniform bounds (union over the wave's 8 adjacent dets)
    #pragma unroll
    for (int m = 1; m < 64; m <<= 1) {
        klo = min(klo, __shfl_xor(klo, m, 64));
        khi = max(khi, __shfl_xor(khi, m, 64));
    }
    klo = __builtin_amdgcn_readfirstlane(klo);
    khi = __builtin_amdgcn_readfirstlane(khi);

    const uint2* __restrict__ Pb = P + (PSTRIDE + 1);   // fold +1 row/col pad offset

    const float tb = fmaf((float)klo, dt8, tstart);
    float col = fmaf(-tb, c2, sx);
    float row = fmaf(-tb, s2, sy);
    const float dcol = -dt8 * c2;
    const float drow = -dt8 * s2;

    float acc = 0.0f;
    #pragma unroll 4
    for (int k = klo; k <= khi; ++k) {
        // branch-free clamp into the zero-pad ring: indices land in [-1,416]
        const float colc = fminf(fmaxf(col, -1.0f), 416.5f);
        const float rowc = fminf(fmaxf(row, -1.0f), 416.5f);
        const int ci = (int)floorf(colc);
        const int ri = (int)floorf(rowc);
        const float wc = colc - (float)ci;
        const float wr = rowc - (float)ri;

        const uint2 u = Pb[ri * PSTRIDE + ci];
        const float v00 = __uint_as_float(u.x << 16);
        const float v01 = __uint_as_float(u.x & 0xffff0000u);
        const float v10 = __uint_as_float(u.y << 16);
        const float v11 = __uint_as_float(u.y & 0xffff0000u);

        const float top = fmaf(wc, v01 - v00, v00);
        const float bot = fmaf(wc, v11 - v10, v10);
        acc = fmaf(wr, bot - top, acc + top);

        col += dcol;
        row += drow;
    }

    // sum over the 8 sample-phases (lane bits 0-2)
    #pragma unroll
    for (int m = 1; m < 8; m <<= 1) acc += __shfl_xor(acc, m, 64);
    float sq = acc * acc;           // identical across each det's 8 lanes
    // sum over the 8 det groups (lane bits 3-5): each group counted once
    #pragma unroll
    for (int m = 8; m < 64; m <<= 1) sq += __shfl_xor(sq, m, 64);

    __shared__ float wsum[4];
    if (lane == 0) wsum[threadIdx.x >> 6] = sq;
    __syncthreads();
    if (threadIdx.x == 0)
        atomicAdd(out, (wsum[0] + wsum[1] + wsum[2] + wsum[3]) * coef);
}

// ---------------------------------------------------------------------------
// Fallback (ws too small): fused one-thread-per-ray fp32 gather version.
// ---------------------------------------------------------------------------
__global__ __launch_bounds__(256) void proj_fused(const float* __restrict__ imgA,
                                                  const float* __restrict__ imgB,
                                                  float* __restrict__ out,
                                                  float theta_step, float gmax,
                                                  float gstep, float t0,
                                                  float dtstep, float coef) {
    const int idx = blockIdx.x * 256 + threadIdx.x;
    const int a  = idx / N_DET;
    const int dd = idx - a * N_DET;
    const float theta = (float)a * theta_step;
    const float gamma = fmaf((float)dd, gstep, -gmax);
    float s1, c1, s2, c2;
    sincosf(theta, &s1, &c1);
    sincosf(theta + gamma, &s2, &c2);
    const float sx = 1075.0f * c1 + 207.5f;
    const float sy = 1075.0f * s1 + 207.5f;
    float acc = 0.0f;
    #pragma unroll 4
    for (int s = 0; s < N_SAMP; ++s) {
        const float t   = fmaf((float)s, dtstep, t0);
        const float col = fmaf(-t, c2, sx);
        const float row = fmaf(-t, s2, sy);
        const float c0 = floorf(col);
        const float r0 = floorf(row);
        const float wc = col - c0;
        const float wr = row - r0;
        const int ci = (int)c0;
        const int ri = (int)r0;
        auto G = [&](int r, int c) -> float {
            if ((unsigned)r < (unsigned)IMG && (unsigned)c < (unsigned)IMG)
                return imgA[r * IMG + c] - imgB[r * IMG + c];
            return 0.0f;
        };
        const float v00 = G(ri, ci);
        const float v01 = G(ri, ci + 1);
        const float v10 = G(ri + 1, ci);
        const float v11 = G(ri + 1, ci + 1);
        const float top = fmaf(wc, v01 - v00, v00);
        const float bot = fmaf(wc, v11 - v10, v10);
        acc += fmaf(wr, bot - top, top);
    }
    float sq = acc * acc;
    #pragma unroll
    for (int o = 32; o > 0; o >>= 1) sq += __shfl_down(sq, o, 64);
    __shared__ float wsum[4];
    const int lane = threadIdx.x & 63;
    if (lane == 0) wsum[threadIdx.x >> 6] = sq;
    __syncthreads();
    if (threadIdx.x == 0)
        atomicAdd(out, (wsum[0] + wsum[1] + wsum[2] + wsum[3]) * coef);
}

extern "C" void kernel_launch(void* const* d_in, const int* in_sizes, int n_in,
                              void* d_out, int out_size, void* d_ws, size_t ws_size,
                              hipStream_t stream) {
    const float* in = (const float*)d_in[0];
    const float* tg = (const float*)d_in[1];
    float* out = (float*)d_out;

    const double half_diag = (IMG / 2.0) * sqrt(2.0);
    const double ray_len   = IMG * sqrt(2.0);
    const float  gmax      = (float)asin(half_diag / 1075.0);
    const float  gstep     = (float)(2.0 * (double)gmax / (N_DET - 1));
    const float  t0        = (float)(1075.0 - ray_len / 2.0);
    const float  dtstep    = (float)(ray_len / (N_SAMP - 1));
    const float  theta_step = (float)(2.0 * M_PI / N_ANG);
    const double dt        = ray_len / (N_SAMP - 1);
    const double SCALE     = 512.0 / 416.0 * 0.03;
    const float  coef      = (float)(dt * dt * SCALE / ((double)N_ANG * N_DET));

    const int n_rays = N_ANG * N_DET;            // 133120
    if (ws_size >= PBYTES) {
        uint2* P = (uint2*)d_ws;
        const int n_ent = PROWS * PSTRIDE;
        pack_kernel<<<(n_ent + 255) / 256, 256, 0, stream>>>(in, tg, P, out);
        // 8 dets/wave -> 16640 waves -> 4160 blocks of 4 waves
        proj_packed<<<(n_rays / 8) / 4, 256, 0, stream>>>(
            P, out, theta_step, gmax, gstep, t0, dtstep, coef);
    } else {
        zero_out_kernel<<<1, 64, 0, stream>>>(out);
        proj_fused<<<n_rays / 256, 256, 0, stream>>>(
            in, tg, out, theta_step, gmax, gstep, t0, dtstep, coef);
    }
}